// Round 14
// baseline (94.931 us; speedup 1.0000x reference)
//
#include <hip/hip_runtime.h>
#include <hip/hip_bf16.h>
#include <stdint.h>

typedef __attribute__((ext_vector_type(8)))  __bf16 bf16x8;
typedef __attribute__((ext_vector_type(16))) float  f32x16;

#define B_  2
#define H_  16
#define S_  2048
#define D_  128
#define BH_ (B_*H_)

__device__ __forceinline__ uint32_t f2bf1(float f){
  uint32_t u = __builtin_bit_cast(uint32_t, f);
  return (u + 0x7fffu + ((u >> 16) & 1u)) >> 16;
}
__device__ __forceinline__ uint32_t pk2(float a, float b){
  return f2bf1(a) | (f2bf1(b) << 16);
}
__device__ __forceinline__ float bf2f(unsigned short u){
  return __builtin_bit_cast(float, (uint32_t)u << 16);
}
__device__ __forceinline__ float max3f(float a, float b, float c){
  return fmaxf(fmaxf(a, b), c);   // clang fuses to v_max3_f32
}

// async global->LDS, 16B/lane, linear LDS dest
__device__ __forceinline__ void gld16(const void* g, void* l){
  __builtin_amdgcn_global_load_lds(
      (const __attribute__((address_space(1))) void*)g,
      (__attribute__((address_space(3))) void*)(uintptr_t)l, 16, 0, 0);
}

// CU-triple-balanced split table: code = qb*4 + mode; mode 0=full,
// 1=kv-chunk A (t in [0,2qb+2)), 2=kv-chunk B (t in [2qb+2,4qb+4), owns diag).
// Dispatch model: CU hosts blocks (u, u+8, u+16); each triple sums to 68 iters:
// (32,32,4)(32,28,8)(30,26,12)(30,22,16)(28,22,18)(28,20,20)(26,24,18)(24,24,20)
__device__ const unsigned char SPLIT_TAB[24] = {
  61, 62, 57, 58, 53, 54, 49, 45,   // u0-7 : 15A 15B 14A 14B 13A 13B 12A 11A
  28, 24, 50, 41, 42, 37, 46, 20,   // u8-15: f7  f6  12B 10A 10B 9A  11B f5
   0,  4,  8, 12, 33, 38, 34, 16    // u16+ : f0  f1  f2  f3  8A  9B  8B  f4
};

// ---------- fused pre-pass: K->bf16 and V->Vt(bf16, transposed) ----------
__global__ void prep(const float* __restrict__ K, const float* __restrict__ V,
                     unsigned short* __restrict__ Kb, unsigned short* __restrict__ Vt){
  __shared__ __attribute__((aligned(16))) unsigned short t[64*68];
  const int kv0 = blockIdx.x * 64, d0 = blockIdx.y * 64, bh = blockIdx.z;
  const int tid = threadIdx.x;
  const float* Vp = V + (size_t)bh * S_ * D_;
  const float* Kp = K + (size_t)bh * S_ * D_;
  unsigned short* Ko = Kb + (size_t)bh * S_ * D_;
  for (int i = 0; i < 4; i++){
    int f = tid + i*256;
    int kv = f >> 4, c4 = f & 15;
    size_t idx = (size_t)(kv0+kv)*D_ + d0 + c4*4;
    float4 k = *(const float4*)(Kp + idx);
    *(uint2*)(Ko + idx) = make_uint2(pk2(k.x,k.y), pk2(k.z,k.w));
  }
  for (int i = 0; i < 4; i++){
    int f = tid + i*256;
    int kv = f >> 4, c4 = f & 15;
    float4 v = *(const float4*)(Vp + (size_t)(kv0+kv)*D_ + d0 + c4*4);
    *(uint2*)&t[kv*68 + c4*4] = make_uint2(pk2(v.x,v.y), pk2(v.z,v.w));
  }
  __syncthreads();
  unsigned short* Vo = Vt + (size_t)bh * D_ * S_;
  for (int i = 0; i < 4; i++){
    int g = tid + i*256;
    int d = g >> 4, c = g & 15, kv = c*4;
    ushort4 o;
    o.x = t[(kv+0)*68 + d];
    o.y = t[(kv+1)*68 + d];
    o.z = t[(kv+2)*68 + d];
    o.w = t[(kv+3)*68 + d];
    *(ushort4*)(Vo + (size_t)(d0+d)*S_ + kv0 + kv) = o;
  }
}

// ---------- flash-attention: KVBLK=32, 32x32 MFMA, in-register P, dbuf K/V ----------
// R11-proven inner loop: 4 waves x 32 q-rows, 32KB LDS, (256,3) -> 3 blocks/CU.
__global__ __launch_bounds__(256, 3)
void attn_fwd(const float* __restrict__ Q, const unsigned short* __restrict__ Kb,
              const unsigned short* __restrict__ Vt, float* __restrict__ Out,
              unsigned short* __restrict__ Opart, float* __restrict__ MLpart,
              int splitFlag){
  __shared__ __attribute__((aligned(16))) unsigned short Klds[2][32*128]; // [kv][d] swz ^((kv&15)<<4)
  __shared__ __attribute__((aligned(16))) unsigned short Vlds[2][128*32]; // [d][kv] swz ^(((d>>1)&3)<<4)

  const int bi = blockIdx.x;
  const int bh = (bi & 7) + 8*((bi >> 3) & 3);
  const int u  = bi >> 5;
  int qb, mode;
  if (splitFlag){ int c = SPLIT_TAB[u]; qb = c >> 2; mode = c & 3; }
  else { qb = (u < 8) ? (15 - u) : (u - 8); mode = 0; }

  const int tid  = threadIdx.x;
  const int wave = tid >> 6, lane = tid & 63;
  const int q32  = lane & 31, hf = lane >> 5;
  const int wq0  = qb*128 + wave*32;
  const int t0   = (mode == 2) ? 2*qb + 2 : 0;
  const int tEnd = (mode == 1) ? 2*qb + 2 : 4*qb + 4;
  const int dtw  = (mode == 1) ? (1 << 30) : (4*qb + wave);
  const float qs = 0.08838834764831845f * 1.44269504088896f; // scale*log2(e)

  const char* Kg = (const char*)(Kb + (size_t)bh * S_ * D_);
  const char* Vg = (const char*)(Vt + (size_t)bh * D_ * S_);

  // staging source offsets (pre-swizzled; LDS dest linear p = wave*2048+i*1024+lane*16)
  uint32_t koff[2], voff[2];
  #pragma unroll
  for (int i = 0; i < 2; i++){
    int kr = wave*8 + i*4 + (lane >> 4);          // K row (256B rows)
    koff[i] = kr*256 + (((lane & 15) ^ (kr & 15)) << 4);
    int vr = wave*32 + i*16 + (lane >> 2);        // V row d (64B rows)
    voff[i] = vr*(S_*2) + (((lane & 3) ^ ((vr >> 1) & 3)) << 4);
  }

  auto stage = [&](int buf, int t){
    const char* kp = Kg + t*8192;    // 32 rows * 256 B
    const char* vp = Vg + t*64;      // 32 kv * 2 B
    char* kd = (char*)&Klds[buf][0] + wave*2048;
    char* vd = (char*)&Vlds[buf][0] + wave*2048;
    #pragma unroll
    for (int i = 0; i < 2; i++){
      gld16(kp + koff[i], kd + i*1024);
      gld16(vp + voff[i], vd + i*1024);
    }
  };

  // Q fragments, pre-scaled: lane holds Q[wq0+q32][ds*16 + hf*8 + j]
  uint4 qf[8];
  {
    const float* Qp = Q + ((size_t)bh * S_ + (wq0 + q32)) * D_ + hf*8;
    #pragma unroll
    for (int ds = 0; ds < 8; ds++){
      float4 a = *(const float4*)(Qp + ds*16);
      float4 b = *(const float4*)(Qp + ds*16 + 4);
      bf16x8 q8;
      q8[0] = (__bf16)(a.x*qs); q8[1] = (__bf16)(a.y*qs);
      q8[2] = (__bf16)(a.z*qs); q8[3] = (__bf16)(a.w*qs);
      q8[4] = (__bf16)(b.x*qs); q8[5] = (__bf16)(b.y*qs);
      q8[6] = (__bf16)(b.z*qs); q8[7] = (__bf16)(b.w*qs);
      qf[ds] = __builtin_bit_cast(uint4, q8);
    }
  }

  f32x16 o[4];
  #pragma unroll
  for (int db = 0; db < 4; db++) o[db] = (f32x16)(0.f);
  float m_run = -INFINITY, l_run = 0.f;

  stage(0, t0);
  __syncthreads();

  int cur = 0;
  for (int t = t0; t < tEnd; ++t){
    if (t + 1 < tEnd) stage(cur ^ 1, t + 1);   // prefetch; drains at end barrier

    if (t <= dtw){
      const bool diag = (t == dtw);
      const char* Kc = (const char*)&Klds[cur][0];
      const char* Vc = (const char*)&Vlds[cur][0];

      // ---- swapped QK^T: S^T = mfma(A=K, B=Q^T), 32x32x16
      f32x16 sa = (f32x16)(0.f);
      __builtin_amdgcn_s_setprio(1);
      #pragma unroll
      for (int ds = 0; ds < 8; ds++){
        int cb = (q32*256 + ds*32 + hf*16) ^ ((q32 & 15) << 4);
        bf16x8 kf = *(const bf16x8*)(Kc + cb);
        sa = __builtin_amdgcn_mfma_f32_32x32x16_bf16(
               kf, __builtin_bit_cast(bf16x8, qf[ds]), sa, 0, 0, 0);
      }
      __builtin_amdgcn_s_setprio(0);

      // ---- online softmax (log2 domain, defer-max); lane owns q-row q32;
      // its 16 regs cover kv = (r&3)+8*(r>>2)+4hf; partner lane^32 has the rest.
      float p[16];
      const int q_abs = wq0 + q32;
      #pragma unroll
      for (int r = 0; r < 16; r++){
        float s = sa[r];
        if (diag){
          int kvl = t*32 + (r & 3) + 8*(r >> 2) + 4*hf;
          if (kvl > q_abs) s = -1e30f;
        }
        p[r] = s;
      }
      // row-max via max3 tree
      float a0 = max3f(p[0],  p[1],  p[2]);
      float a1 = max3f(p[3],  p[4],  p[5]);
      float a2 = max3f(p[6],  p[7],  p[8]);
      float a3 = max3f(p[9],  p[10], p[11]);
      float a4 = max3f(p[12], p[13], p[14]);
      float pm = fmaxf(max3f(a0, a1, a2), max3f(a3, a4, p[15]));
      pm = fmaxf(pm, __shfl_xor(pm, 32));
      if (__any(pm > m_run + 11.5f)){
        float mn  = fmaxf(m_run, pm);
        float fac = exp2f(m_run - mn);
        float fv[16];
        #pragma unroll
        for (int r = 0; r < 16; r++) fv[r] = __shfl(fac, (r & 3) + 8*(r >> 2) + 4*hf);
        #pragma unroll
        for (int db = 0; db < 4; db++)
          #pragma unroll
          for (int r = 0; r < 16; r++) o[db][r] *= fv[r];
        l_run *= fac;
        m_run = mn;
      }
      float rs = 0.f;
      #pragma unroll
      for (int i = 0; i < 16; i++){ p[i] = exp2f(p[i] - m_run); rs += p[i]; }
      rs += __shfl_xor(rs, 32);
      l_run += rs;

      // ---- pack P to bf16 pairs: Wp[m][tt] = pk(kv = 8m+4hf+2tt, +1)
      uint32_t Wp[4][2];
      #pragma unroll
      for (int m = 0; m < 4; m++){
        #pragma unroll
        for (int tt = 0; tt < 2; tt++){
          float lo = p[4*m + 2*tt];
          float hi = p[4*m + 2*tt + 1];
          asm("v_cvt_pk_bf16_f32 %0, %1, %2" : "=v"(Wp[m][tt]) : "v"(lo), "v"(hi));
        }
      }

      // ---- PV: A = P (permlane32_swap redistribution), B = V from LDS
      __builtin_amdgcn_s_setprio(1);
      #pragma unroll
      for (int Ks = 0; Ks < 2; Ks++){
        uint32_t d0 = Wp[2*Ks][0], d2 = Wp[2*Ks + 1][0];
        asm volatile("v_permlane32_swap_b32 %0, %1" : "+v"(d0), "+v"(d2));
        uint32_t d1 = Wp[2*Ks][1], d3 = Wp[2*Ks + 1][1];
        asm volatile("v_permlane32_swap_b32 %0, %1" : "+v"(d1), "+v"(d3));
        uint4 pw = make_uint4(d0, d1, d2, d3);
        bf16x8 paf = __builtin_bit_cast(bf16x8, pw);
        #pragma unroll
        for (int db = 0; db < 4; db++){
          int row = db*32 + q32;
          int vb = (row*64 + Ks*32 + hf*16) ^ (((row >> 1) & 3) << 4);
          bf16x8 vf = *(const bf16x8*)(Vc + vb);
          o[db] = __builtin_amdgcn_mfma_f32_32x32x16_bf16(paf, vf, o[db], 0, 0, 0);
        }
      }
      __builtin_amdgcn_s_setprio(0);
    }

    __syncthreads();   // drains prefetch + publishes buf[cur^1]
    cur ^= 1;
  }

  // ---- epilogue
  if (mode == 0){
    float rl[16];
    #pragma unroll
    for (int r = 0; r < 16; r++)
      rl[r] = 1.f / __shfl(l_run, (r & 3) + 8*(r >> 2) + 4*hf);
    float* Op = Out + ((size_t)bh * S_ + wq0) * D_;
    #pragma unroll
    for (int db = 0; db < 4; db++){
      #pragma unroll
      for (int r = 0; r < 16; r++){
        int qrow = (r & 3) + 8*(r >> 2) + 4*hf;
        Op[(size_t)qrow*D_ + db*32 + q32] = o[db][r] * rl[r];
      }
    }
  } else {
    const int slot = (bh*8 + (qb - 8))*2 + (mode - 1);
    unsigned short* Po = Opart + (size_t)slot * (128*128);
    float* Ml = MLpart + (size_t)slot * 256;
    #pragma unroll
    for (int db = 0; db < 4; db++){
      #pragma unroll
      for (int r = 0; r < 16; r++){
        int row = wave*32 + (r & 3) + 8*(r >> 2) + 4*hf;
        __bf16 bv = (__bf16)o[db][r];
        Po[row*128 + db*32 + q32] = __builtin_bit_cast(unsigned short, bv);
      }
    }
    if (hf == 0){
      Ml[(wave*32 + q32)*2 + 0] = m_run;
      Ml[(wave*32 + q32)*2 + 1] = l_run;
    }
  }
}

// ---------- combine kernel: merge the two kv-chunks of qb>=8 ----------
__global__ __launch_bounds__(256)
void combine(const unsigned short* __restrict__ Opart,
             const float* __restrict__ MLpart, float* __restrict__ Out){
  const int blk = blockIdx.x;           // 0..255 = bh*8 + (qb-8)
  const int bh = blk >> 3, qq = blk & 7;
  const unsigned short* A  = Opart + (size_t)(blk*2) * (128*128);
  const unsigned short* Bp = A + 128*128;
  const float* MA = MLpart + (size_t)(blk*2) * 256;
  const float* MB = MA + 256;

  const int row  = threadIdx.x >> 1;
  const int half = threadIdx.x & 1;
  float mA = MA[row*2], lA = MA[row*2 + 1];
  float mB = MB[row*2], lB = MB[row*2 + 1];
  float M  = fmaxf(mA, mB);
  float wA = exp2f(mA - M), wB = exp2f(mB - M);
  float inv = 1.f / (lA*wA + lB*wB);
  wA *= inv; wB *= inv;

  const unsigned short* Ar = A  + row*128 + half*64;
  const unsigned short* Br = Bp + row*128 + half*64;
  float* Or = Out + ((size_t)bh * S_ + (qq + 8)*128 + row) * D_ + half*64;
  #pragma unroll
  for (int c = 0; c < 64; c += 8){
    ushort4 a0 = *(const ushort4*)(Ar + c), a1 = *(const ushort4*)(Ar + c + 4);
    ushort4 b0 = *(const ushort4*)(Br + c), b1 = *(const ushort4*)(Br + c + 4);
    const unsigned short av[8] = {a0.x,a0.y,a0.z,a0.w,a1.x,a1.y,a1.z,a1.w};
    const unsigned short bv[8] = {b0.x,b0.y,b0.z,b0.w,b1.x,b1.y,b1.z,b1.w};
    #pragma unroll
    for (int j = 0; j < 8; j++){
      Or[c + j] = bf2f(av[j])*wA + bf2f(bv[j])*wB;
    }
  }
}

extern "C" void kernel_launch(void* const* d_in, const int* in_sizes, int n_in,
                              void* d_out, int out_size, void* d_ws, size_t ws_size,
                              hipStream_t stream){
  const float* Q = (const float*)d_in[0];
  const float* K = (const float*)d_in[1];
  const float* V = (const float*)d_in[2];
  float* Out = (float*)d_out;

  unsigned short* Kb = (unsigned short*)d_ws;                 // 16.78 MB
  unsigned short* Vt = Kb + (size_t)BH_ * S_ * D_;            // 16.78 MB
  unsigned short* Opart = Vt + (size_t)BH_ * S_ * D_;         // 512 x 32KB = 16.78 MB
  float* MLpart = (float*)(Opart + (size_t)512 * 128 * 128);  // 0.52 MB

  const size_t need = (size_t)BH_*S_*D_*2*3 + (size_t)512*256*4;
  const int split = (ws_size >= need) ? 1 : 0;

  prep<<<dim3(S_/64, D_/64, BH_), 256, 0, stream>>>(K, V, Kb, Vt);
  attn_fwd<<<split ? 768 : 512, 256, 0, stream>>>(Q, Kb, Vt, Out, Opart, MLpart, split);
  if (split) combine<<<256, 256, 0, stream>>>(Opart, MLpart, Out);
}

// Round 15
// 84.769 us; speedup vs baseline: 1.1199x; 1.1199x over previous
//
#include <hip/hip_runtime.h>
#include <hip/hip_bf16.h>
#include <stdint.h>

typedef __attribute__((ext_vector_type(8)))  __bf16 bf16x8;
typedef __attribute__((ext_vector_type(16))) float  f32x16;

#define B_  2
#define H_  16
#define S_  2048
#define D_  128
#define BH_ (B_*H_)

__device__ __forceinline__ uint32_t f2bf1(float f){
  uint32_t u = __builtin_bit_cast(uint32_t, f);
  return (u + 0x7fffu + ((u >> 16) & 1u)) >> 16;
}
__device__ __forceinline__ uint32_t pk2(float a, float b){
  return f2bf1(a) | (f2bf1(b) << 16);
}
__device__ __forceinline__ float bf2f(unsigned short u){
  return __builtin_bit_cast(float, (uint32_t)u << 16);
}
__device__ __forceinline__ float max3f(float a, float b, float c){
  return fmaxf(fmaxf(a, b), c);   // clang fuses to v_max3_f32
}
// native 2^x: single v_exp_f32 (trans pipe), ~1 ULP — avoids OCML libcall
__device__ __forceinline__ float ex2(float x){
  float r;
  asm("v_exp_f32 %0, %1" : "=v"(r) : "v"(x));
  return r;
}

// async global->LDS, 16B/lane, linear LDS dest
__device__ __forceinline__ void gld16(const void* g, void* l){
  __builtin_amdgcn_global_load_lds(
      (const __attribute__((address_space(1))) void*)g,
      (__attribute__((address_space(3))) void*)(uintptr_t)l, 16, 0, 0);
}

// R13-proven coarse split: code = qb*4 + mode; mode 0=full,
// 1=kv-chunk A (t in [0,2qb+2)), 2=kv-chunk B (t in [2qb+2,4qb+4), owns diag).
// LPT heavy-first.
__device__ const unsigned char SPLIT_TAB[24] = {
  15*4+1,15*4+2, 7*4+0, 14*4+1,14*4+2, 13*4+1,13*4+2, 6*4+0,
  12*4+1,12*4+2, 11*4+1,11*4+2, 5*4+0, 10*4+1,10*4+2, 9*4+1,9*4+2,
  4*4+0, 8*4+1,8*4+2, 3*4+0, 2*4+0, 1*4+0, 0*4+0
};

// ---------- fused pre-pass: K->bf16 and V->Vt(bf16, transposed) ----------
__global__ void prep(const float* __restrict__ K, const float* __restrict__ V,
                     unsigned short* __restrict__ Kb, unsigned short* __restrict__ Vt){
  __shared__ __attribute__((aligned(16))) unsigned short t[64*68];
  const int kv0 = blockIdx.x * 64, d0 = blockIdx.y * 64, bh = blockIdx.z;
  const int tid = threadIdx.x;
  const float* Vp = V + (size_t)bh * S_ * D_;
  const float* Kp = K + (size_t)bh * S_ * D_;
  unsigned short* Ko = Kb + (size_t)bh * S_ * D_;
  for (int i = 0; i < 4; i++){
    int f = tid + i*256;
    int kv = f >> 4, c4 = f & 15;
    size_t idx = (size_t)(kv0+kv)*D_ + d0 + c4*4;
    float4 k = *(const float4*)(Kp + idx);
    *(uint2*)(Ko + idx) = make_uint2(pk2(k.x,k.y), pk2(k.z,k.w));
  }
  for (int i = 0; i < 4; i++){
    int f = tid + i*256;
    int kv = f >> 4, c4 = f & 15;
    float4 v = *(const float4*)(Vp + (size_t)(kv0+kv)*D_ + d0 + c4*4);
    *(uint2*)&t[kv*68 + c4*4] = make_uint2(pk2(v.x,v.y), pk2(v.z,v.w));
  }
  __syncthreads();
  unsigned short* Vo = Vt + (size_t)bh * D_ * S_;
  for (int i = 0; i < 4; i++){
    int g = tid + i*256;
    int d = g >> 4, c = g & 15, kv = c*4;
    ushort4 o;
    o.x = t[(kv+0)*68 + d];
    o.y = t[(kv+1)*68 + d];
    o.z = t[(kv+2)*68 + d];
    o.w = t[(kv+3)*68 + d];
    *(ushort4*)(Vo + (size_t)(d0+d)*S_ + kv0 + kv) = o;
  }
}

// ---------- flash-attention: KVBLK=32, 32x32 MFMA, in-register P, dbuf K/V ----------
// R11-proven inner loop: 4 waves x 32 q-rows, 32KB LDS, (256,3) -> 3 blocks/CU.
__global__ __launch_bounds__(256, 3)
void attn_fwd(const float* __restrict__ Q, const unsigned short* __restrict__ Kb,
              const unsigned short* __restrict__ Vt, float* __restrict__ Out,
              unsigned short* __restrict__ Opart, float* __restrict__ MLpart,
              int splitFlag){
  __shared__ __attribute__((aligned(16))) unsigned short Klds[2][32*128]; // [kv][d] swz ^((kv&15)<<4)
  __shared__ __attribute__((aligned(16))) unsigned short Vlds[2][128*32]; // [d][kv] swz ^(((d>>1)&3)<<4)

  const int bi = blockIdx.x;
  const int bh = (bi & 7) + 8*((bi >> 3) & 3);
  const int u  = bi >> 5;
  int qb, mode;
  if (splitFlag){ int c = SPLIT_TAB[u]; qb = c >> 2; mode = c & 3; }
  else { qb = (u < 8) ? (15 - u) : (u - 8); mode = 0; }

  const int tid  = threadIdx.x;
  const int wave = tid >> 6, lane = tid & 63;
  const int q32  = lane & 31, hf = lane >> 5;
  const int wq0  = qb*128 + wave*32;
  const int t0   = (mode == 2) ? 2*qb + 2 : 0;
  const int tEnd = (mode == 1) ? 2*qb + 2 : 4*qb + 4;
  const int dtw  = (mode == 1) ? (1 << 30) : (4*qb + wave);
  const float qs = 0.08838834764831845f * 1.44269504088896f; // scale*log2(e)

  const char* Kg = (const char*)(Kb + (size_t)bh * S_ * D_);
  const char* Vg = (const char*)(Vt + (size_t)bh * D_ * S_);

  // staging source offsets (pre-swizzled; LDS dest linear p = wave*2048+i*1024+lane*16)
  uint32_t koff[2], voff[2];
  #pragma unroll
  for (int i = 0; i < 2; i++){
    int kr = wave*8 + i*4 + (lane >> 4);          // K row (256B rows)
    koff[i] = kr*256 + (((lane & 15) ^ (kr & 15)) << 4);
    int vr = wave*32 + i*16 + (lane >> 2);        // V row d (64B rows)
    voff[i] = vr*(S_*2) + (((lane & 3) ^ ((vr >> 1) & 3)) << 4);
  }

  auto stage = [&](int buf, int t){
    const char* kp = Kg + t*8192;    // 32 rows * 256 B
    const char* vp = Vg + t*64;      // 32 kv * 2 B
    char* kd = (char*)&Klds[buf][0] + wave*2048;
    char* vd = (char*)&Vlds[buf][0] + wave*2048;
    #pragma unroll
    for (int i = 0; i < 2; i++){
      gld16(kp + koff[i], kd + i*1024);
      gld16(vp + voff[i], vd + i*1024);
    }
  };

  // Q fragments, pre-scaled: lane holds Q[wq0+q32][ds*16 + hf*8 + j]
  uint4 qf[8];
  {
    const float* Qp = Q + ((size_t)bh * S_ + (wq0 + q32)) * D_ + hf*8;
    #pragma unroll
    for (int ds = 0; ds < 8; ds++){
      float4 a = *(const float4*)(Qp + ds*16);
      float4 b = *(const float4*)(Qp + ds*16 + 4);
      bf16x8 q8;
      q8[0] = (__bf16)(a.x*qs); q8[1] = (__bf16)(a.y*qs);
      q8[2] = (__bf16)(a.z*qs); q8[3] = (__bf16)(a.w*qs);
      q8[4] = (__bf16)(b.x*qs); q8[5] = (__bf16)(b.y*qs);
      q8[6] = (__bf16)(b.z*qs); q8[7] = (__bf16)(b.w*qs);
      qf[ds] = __builtin_bit_cast(uint4, q8);
    }
  }

  f32x16 o[4];
  #pragma unroll
  for (int db = 0; db < 4; db++) o[db] = (f32x16)(0.f);
  float m_run = -INFINITY, l_run = 0.f;

  stage(0, t0);
  __syncthreads();

  int cur = 0;
  for (int t = t0; t < tEnd; ++t){
    if (t + 1 < tEnd) stage(cur ^ 1, t + 1);   // prefetch; drains at end barrier

    if (t <= dtw){
      const bool diag = (t == dtw);
      const char* Kc = (const char*)&Klds[cur][0];
      const char* Vc = (const char*)&Vlds[cur][0];

      // ---- swapped QK^T: S^T = mfma(A=K, B=Q^T), 32x32x16
      f32x16 sa = (f32x16)(0.f);
      __builtin_amdgcn_s_setprio(1);
      #pragma unroll
      for (int ds = 0; ds < 8; ds++){
        int cb = (q32*256 + ds*32 + hf*16) ^ ((q32 & 15) << 4);
        bf16x8 kf = *(const bf16x8*)(Kc + cb);
        sa = __builtin_amdgcn_mfma_f32_32x32x16_bf16(
               kf, __builtin_bit_cast(bf16x8, qf[ds]), sa, 0, 0, 0);
      }
      __builtin_amdgcn_s_setprio(0);

      // ---- online softmax (log2 domain, defer-max); lane owns q-row q32;
      // its 16 regs cover kv = (r&3)+8*(r>>2)+4hf; partner lane^32 has the rest.
      float p[16];
      const int q_abs = wq0 + q32;
      #pragma unroll
      for (int r = 0; r < 16; r++){
        float s = sa[r];
        if (diag){
          int kvl = t*32 + (r & 3) + 8*(r >> 2) + 4*hf;
          if (kvl > q_abs) s = -1e30f;
        }
        p[r] = s;
      }
      // row-max via max3 tree
      float a0 = max3f(p[0],  p[1],  p[2]);
      float a1 = max3f(p[3],  p[4],  p[5]);
      float a2 = max3f(p[6],  p[7],  p[8]);
      float a3 = max3f(p[9],  p[10], p[11]);
      float a4 = max3f(p[12], p[13], p[14]);
      float pm = fmaxf(max3f(a0, a1, a2), max3f(a3, a4, p[15]));
      pm = fmaxf(pm, __shfl_xor(pm, 32));
      if (__any(pm > m_run + 11.5f)){
        float mn  = fmaxf(m_run, pm);
        float fac = ex2(m_run - mn);           // 0 when m_run == -inf
        float fv[16];
        #pragma unroll
        for (int r = 0; r < 16; r++) fv[r] = __shfl(fac, (r & 3) + 8*(r >> 2) + 4*hf);
        #pragma unroll
        for (int db = 0; db < 4; db++)
          #pragma unroll
          for (int r = 0; r < 16; r++) o[db][r] *= fv[r];
        l_run *= fac;
        m_run = mn;
      }
      float rs = 0.f;
      #pragma unroll
      for (int i = 0; i < 16; i++){ p[i] = ex2(p[i] - m_run); rs += p[i]; }
      rs += __shfl_xor(rs, 32);
      l_run += rs;

      // ---- pack P to bf16 pairs: Wp[m][tt] = pk(kv = 8m+4hf+2tt, +1)
      uint32_t Wp[4][2];
      #pragma unroll
      for (int m = 0; m < 4; m++){
        #pragma unroll
        for (int tt = 0; tt < 2; tt++){
          float lo = p[4*m + 2*tt];
          float hi = p[4*m + 2*tt + 1];
          asm("v_cvt_pk_bf16_f32 %0, %1, %2" : "=v"(Wp[m][tt]) : "v"(lo), "v"(hi));
        }
      }

      // ---- PV: A = P (permlane32_swap redistribution), B = V from LDS
      __builtin_amdgcn_s_setprio(1);
      #pragma unroll
      for (int Ks = 0; Ks < 2; Ks++){
        uint32_t d0 = Wp[2*Ks][0], d2 = Wp[2*Ks + 1][0];
        asm volatile("v_permlane32_swap_b32 %0, %1" : "+v"(d0), "+v"(d2));
        uint32_t d1 = Wp[2*Ks][1], d3 = Wp[2*Ks + 1][1];
        asm volatile("v_permlane32_swap_b32 %0, %1" : "+v"(d1), "+v"(d3));
        uint4 pw = make_uint4(d0, d1, d2, d3);
        bf16x8 paf = __builtin_bit_cast(bf16x8, pw);
        #pragma unroll
        for (int db = 0; db < 4; db++){
          int row = db*32 + q32;
          int vb = (row*64 + Ks*32 + hf*16) ^ (((row >> 1) & 3) << 4);
          bf16x8 vf = *(const bf16x8*)(Vc + vb);
          o[db] = __builtin_amdgcn_mfma_f32_32x32x16_bf16(paf, vf, o[db], 0, 0, 0);
        }
      }
      __builtin_amdgcn_s_setprio(0);
    }

    __syncthreads();   // drains prefetch + publishes buf[cur^1]
    cur ^= 1;
  }

  // ---- epilogue
  if (mode == 0){
    float rl[16];
    #pragma unroll
    for (int r = 0; r < 16; r++)
      rl[r] = 1.f / __shfl(l_run, (r & 3) + 8*(r >> 2) + 4*hf);
    float* Op = Out + ((size_t)bh * S_ + wq0) * D_;
    #pragma unroll
    for (int db = 0; db < 4; db++){
      #pragma unroll
      for (int r = 0; r < 16; r++){
        int qrow = (r & 3) + 8*(r >> 2) + 4*hf;
        Op[(size_t)qrow*D_ + db*32 + q32] = o[db][r] * rl[r];
      }
    }
  } else {
    const int slot = (bh*8 + (qb - 8))*2 + (mode - 1);
    unsigned short* Po = Opart + (size_t)slot * (128*128);
    float* Ml = MLpart + (size_t)slot * 256;
    #pragma unroll
    for (int db = 0; db < 4; db++){
      #pragma unroll
      for (int r = 0; r < 16; r++){
        int row = wave*32 + (r & 3) + 8*(r >> 2) + 4*hf;
        __bf16 bv = (__bf16)o[db][r];
        Po[row*128 + db*32 + q32] = __builtin_bit_cast(unsigned short, bv);
      }
    }
    if (hf == 0){
      Ml[(wave*32 + q32)*2 + 0] = m_run;
      Ml[(wave*32 + q32)*2 + 1] = l_run;
    }
  }
}

// ---------- combine kernel: merge the two kv-chunks of qb>=8 ----------
__global__ __launch_bounds__(256)
void combine(const unsigned short* __restrict__ Opart,
             const float* __restrict__ MLpart, float* __restrict__ Out){
  const int blk = blockIdx.x;           // 0..255 = bh*8 + (qb-8)
  const int bh = blk >> 3, qq = blk & 7;
  const unsigned short* A  = Opart + (size_t)(blk*2) * (128*128);
  const unsigned short* Bp = A + 128*128;
  const float* MA = MLpart + (size_t)(blk*2) * 256;
  const float* MB = MA + 256;

  const int row  = threadIdx.x >> 1;
  const int half = threadIdx.x & 1;
  float mA = MA[row*2], lA = MA[row*2 + 1];
  float mB = MB[row*2], lB = MB[row*2 + 1];
  float M  = fmaxf(mA, mB);
  float wA = exp2f(mA - M), wB = exp2f(mB - M);
  float inv = 1.f / (lA*wA + lB*wB);
  wA *= inv; wB *= inv;

  const unsigned short* Ar = A  + row*128 + half*64;
  const unsigned short* Br = Bp + row*128 + half*64;
  float* Or = Out + ((size_t)bh * S_ + (qq + 8)*128 + row) * D_ + half*64;
  #pragma unroll
  for (int c = 0; c < 64; c += 8){
    ushort4 a0 = *(const ushort4*)(Ar + c), a1 = *(const ushort4*)(Ar + c + 4);
    ushort4 b0 = *(const ushort4*)(Br + c), b1 = *(const ushort4*)(Br + c + 4);
    const unsigned short av[8] = {a0.x,a0.y,a0.z,a0.w,a1.x,a1.y,a1.z,a1.w};
    const unsigned short bv[8] = {b0.x,b0.y,b0.z,b0.w,b1.x,b1.y,b1.z,b1.w};
    #pragma unroll
    for (int j = 0; j < 8; j++){
      Or[c + j] = bf2f(av[j])*wA + bf2f(bv[j])*wB;
    }
  }
}

extern "C" void kernel_launch(void* const* d_in, const int* in_sizes, int n_in,
                              void* d_out, int out_size, void* d_ws, size_t ws_size,
                              hipStream_t stream){
  const float* Q = (const float*)d_in[0];
  const float* K = (const float*)d_in[1];
  const float* V = (const float*)d_in[2];
  float* Out = (float*)d_out;

  unsigned short* Kb = (unsigned short*)d_ws;                 // 16.78 MB
  unsigned short* Vt = Kb + (size_t)BH_ * S_ * D_;            // 16.78 MB
  unsigned short* Opart = Vt + (size_t)BH_ * S_ * D_;         // 512 x 32KB = 16.78 MB
  float* MLpart = (float*)(Opart + (size_t)512 * 128 * 128);  // 0.52 MB

  const size_t need = (size_t)BH_*S_*D_*2*3 + (size_t)512*256*4;
  const int split = (ws_size >= need) ? 1 : 0;

  prep<<<dim3(S_/64, D_/64, BH_), 256, 0, stream>>>(K, V, Kb, Vt);
  attn_fwd<<<split ? 768 : 512, 256, 0, stream>>>(Q, Kb, Vt, Out, Opart, MLpart, split);
  if (split) combine<<<256, 256, 0, stream>>>(Opart, MLpart, Out);
}